// Round 4
// baseline (491.809 us; speedup 1.0000x reference)
//
#include <hip/hip_runtime.h>
#include <hip/hip_bf16.h>

#define N_NODES 100000
#define N_EDGES 1600000
#define IN_FEAT 256
#define HID_F   128
#define OUT_FT  64
#define NBLK_SCAN ((N_NODES + 255) / 256)   // 391
#define G_GEMM   ((N_NODES + 127) / 128)    // 782
#define G_FILL   ((N_EDGES + 255) / 256)    // 6250
#define G_CAST   ((IN_FEAT * HID_F + HID_F * OUT_FT + 255) / 256)  // 160

typedef unsigned short u16;
typedef __attribute__((ext_vector_type(8))) unsigned short u16x8;
typedef __attribute__((ext_vector_type(8))) short short8;
typedef __attribute__((ext_vector_type(4))) float f32x4;

static __device__ inline u16 f2bf(float f) {
    __hip_bfloat16 h = __float2bfloat16(f);
    return *reinterpret_cast<u16*>(&h);
}

// ---------------- CSR build (+ weight cast piggybacked) ----------------

__global__ void k_count_cast(const int* __restrict__ dstA, int* __restrict__ counts,
                             const float* __restrict__ W1, const float* __restrict__ W2,
                             u16* __restrict__ W1t, u16* __restrict__ W2t) {
    if (blockIdx.x < G_FILL) {
        int e = blockIdx.x * 256 + threadIdx.x;
        if (e < N_EDGES) atomicAdd(&counts[dstA[e]], 1);
    } else {
        int idx = (blockIdx.x - G_FILL) * 256 + threadIdx.x;
        if (idx < IN_FEAT * HID_F) {
            int k = idx / HID_F, n = idx % HID_F;
            W1t[n * IN_FEAT + k] = f2bf(W1[idx]);
        } else {
            int e2 = idx - IN_FEAT * HID_F;
            if (e2 < HID_F * OUT_FT) {
                int k = e2 / OUT_FT, n = e2 % OUT_FT;
                W2t[n * HID_F + k] = f2bf(W2[e2]);
            }
        }
    }
}

// dinv + per-block sum in one pass (same 391-block grid)
__global__ __launch_bounds__(256) void k_dinv_bsum(const int* __restrict__ counts,
                                                   float* __restrict__ dinv,
                                                   int* __restrict__ blksum) {
    int i = blockIdx.x * 256 + threadIdx.x;
    int v = (i < N_NODES) ? counts[i] : 0;
    if (i < N_NODES) dinv[i] = rsqrtf((float)(v + 1));  // +1 self loop
    int s = v;
#pragma unroll
    for (int o = 32; o > 0; o >>= 1) s += __shfl_down(s, o, 64);
    __shared__ int wsum[4];
    if ((threadIdx.x & 63) == 0) wsum[threadIdx.x >> 6] = s;
    __syncthreads();
    if (threadIdx.x == 0) blksum[blockIdx.x] = wsum[0] + wsum[1] + wsum[2] + wsum[3];
}

__global__ __launch_bounds__(512) void k_scanblk(const int* __restrict__ blksum,
                                                 int* __restrict__ blkoff) {
    __shared__ int sm[512];
    int t = threadIdx.x;
    int v = (t < NBLK_SCAN) ? blksum[t] : 0;
    sm[t] = v;
    __syncthreads();
    for (int o = 1; o < 512; o <<= 1) {
        int u = (t >= o) ? sm[t - o] : 0;
        __syncthreads();
        sm[t] += u;
        __syncthreads();
    }
    if (t < NBLK_SCAN) blkoff[t] = sm[t] - v;
}

// offsets + cursor copy (cursor consumed destructively by the fill)
__global__ __launch_bounds__(256) void k_offsets(const int* __restrict__ counts,
                                                 const int* __restrict__ blkoff,
                                                 int* __restrict__ offsets,
                                                 int* __restrict__ cursor) {
    __shared__ int sm[256];
    int t = threadIdx.x;
    int i = blockIdx.x * 256 + t;
    int v = (i < N_NODES) ? counts[i] : 0;
    sm[t] = v;
    __syncthreads();
    for (int o = 1; o < 256; o <<= 1) {
        int u = (t >= o) ? sm[t - o] : 0;
        __syncthreads();
        sm[t] += u;
        __syncthreads();
    }
    if (i < N_NODES) {
        int off = blkoff[blockIdx.x] + sm[t] - v;
        offsets[i] = off;
        cursor[i] = off;
    }
    if (i == N_NODES - 1) offsets[N_NODES] = N_EDGES;
}

// ---------------- fused: MFMA bf16 GEMM layer-1 + CSR fill ----------------
// blocks [0,G_GEMM): hs1 = bf16(dinv * (x @ W1));  blocks [G_GEMM, +G_FILL): csr fill.
// gemm blocks first -> ~3 heavy blocks/CU, fill's tiny latency-bound blocks backfill.

__global__ __launch_bounds__(256) void k_gemm1_fill(
        const float* __restrict__ A, const u16* __restrict__ Bt,
        const float* __restrict__ dinv, u16* __restrict__ C,
        const int* __restrict__ srcA, const int* __restrict__ dstA,
        int* __restrict__ cursor, int* __restrict__ csr) {
    __shared__ u16 As[128][40];  // stride 40: free 2-way bank pattern
    __shared__ u16 Bs[128][40];
    int tid = threadIdx.x;

    if (blockIdx.x >= G_GEMM) {
        int e = (blockIdx.x - G_GEMM) * 256 + tid;
        if (e < N_EDGES) {
            int d = dstA[e];
            int p = atomicAdd(&cursor[d], 1);
            csr[p] = srcA[e];
        }
        return;
    }

    int wv = tid >> 6, lane = tid & 63;
    int m16 = lane & 15, quad = lane >> 4;
    int row0 = blockIdx.x * 128;
    int r = tid >> 1, h = tid & 1;
    int grow_s = row0 + r;
    bool rok = grow_s < N_NODES;

    f32x4 acc[2][8];
#pragma unroll
    for (int i = 0; i < 2; i++)
#pragma unroll
        for (int j = 0; j < 8; j++) acc[i][j] = (f32x4)(0.f);

    for (int k0 = 0; k0 < IN_FEAT; k0 += 32) {
        f32x4 v0 = (f32x4)(0.f), v1 = v0, v2 = v0, v3 = v0;
        if (rok) {
            const f32x4* src = (const f32x4*)&A[(size_t)grow_s * IN_FEAT + k0 + h * 16];
            v0 = src[0]; v1 = src[1]; v2 = src[2]; v3 = src[3];
        }
        u16x8 p0, p1;
#pragma unroll
        for (int j = 0; j < 4; j++) {
            p0[j] = f2bf(v0[j]); p0[4 + j] = f2bf(v1[j]);
            p1[j] = f2bf(v2[j]); p1[4 + j] = f2bf(v3[j]);
        }
        *(u16x8*)&As[r][h * 16] = p0;
        *(u16x8*)&As[r][h * 16 + 8] = p1;
        const u16x8* bsrc = (const u16x8*)&Bt[(size_t)r * IN_FEAT + k0 + h * 16];
        *(u16x8*)&Bs[r][h * 16] = bsrc[0];
        *(u16x8*)&Bs[r][h * 16 + 8] = bsrc[1];
        __syncthreads();

        short8 af0 = *(const short8*)&As[32 * wv + m16][quad * 8];
        short8 af1 = *(const short8*)&As[32 * wv + 16 + m16][quad * 8];
#pragma unroll
        for (int ct = 0; ct < 8; ct++) {
            short8 bf = *(const short8*)&Bs[16 * ct + m16][quad * 8];
            acc[0][ct] = __builtin_amdgcn_mfma_f32_16x16x32_bf16(af0, bf, acc[0][ct], 0, 0, 0);
            acc[1][ct] = __builtin_amdgcn_mfma_f32_16x16x32_bf16(af1, bf, acc[1][ct], 0, 0, 0);
        }
        __syncthreads();
    }
#pragma unroll
    for (int rt = 0; rt < 2; rt++)
#pragma unroll
        for (int r4 = 0; r4 < 4; r4++) {
            int grow = row0 + 32 * wv + 16 * rt + quad * 4 + r4;
            if (grow < N_NODES) {
                float dv = dinv[grow];
#pragma unroll
                for (int ct = 0; ct < 8; ct++)
                    C[(size_t)grow * HID_F + 16 * ct + m16] = f2bf(acc[rt][ct][r4] * dv);
            }
        }
}

// ---------------- MFMA bf16 GEMM, layer 2 ----------------

__global__ __launch_bounds__(256) void k_gemm2(const u16* __restrict__ A,
                                               const u16* __restrict__ Bt,
                                               const float* __restrict__ dinv,
                                               u16* __restrict__ C) {
    __shared__ u16 As[128][40];
    __shared__ u16 Bs[64][40];
    int tid = threadIdx.x;
    int wv = tid >> 6, lane = tid & 63;
    int m16 = lane & 15, quad = lane >> 4;
    int row0 = blockIdx.x * 128;
    int r = tid >> 1, h = tid & 1;
    int grow_s = row0 + r;
    bool rok = grow_s < N_NODES;
    int nb = tid >> 2, q = tid & 3;

    f32x4 acc[2][4];
#pragma unroll
    for (int i = 0; i < 2; i++)
#pragma unroll
        for (int j = 0; j < 4; j++) acc[i][j] = (f32x4)(0.f);

    for (int k0 = 0; k0 < HID_F; k0 += 32) {
        u16x8 a0 = (u16x8)(0), a1v = (u16x8)(0);
        if (rok) {
            const u16x8* src = (const u16x8*)&A[(size_t)grow_s * HID_F + k0 + h * 16];
            a0 = src[0]; a1v = src[1];
        }
        *(u16x8*)&As[r][h * 16] = a0;
        *(u16x8*)&As[r][h * 16 + 8] = a1v;
        *(u16x8*)&Bs[nb][q * 8] = *(const u16x8*)&Bt[(size_t)nb * HID_F + k0 + q * 8];
        __syncthreads();

        short8 af0 = *(const short8*)&As[32 * wv + m16][quad * 8];
        short8 af1 = *(const short8*)&As[32 * wv + 16 + m16][quad * 8];
#pragma unroll
        for (int ct = 0; ct < 4; ct++) {
            short8 bf = *(const short8*)&Bs[16 * ct + m16][quad * 8];
            acc[0][ct] = __builtin_amdgcn_mfma_f32_16x16x32_bf16(af0, bf, acc[0][ct], 0, 0, 0);
            acc[1][ct] = __builtin_amdgcn_mfma_f32_16x16x32_bf16(af1, bf, acc[1][ct], 0, 0, 0);
        }
        __syncthreads();
    }
#pragma unroll
    for (int rt = 0; rt < 2; rt++)
#pragma unroll
        for (int r4 = 0; r4 < 4; r4++) {
            int grow = row0 + 32 * wv + 16 * rt + quad * 4 + r4;
            if (grow < N_NODES) {
                float dv = dinv[grow];
#pragma unroll
                for (int ct = 0; ct < 4; ct++)
                    C[(size_t)grow * OUT_FT + 16 * ct + m16] = f2bf(acc[rt][ct][r4] * dv);
            }
        }
}

// ---------------- aggregation (CSR gather-reduce, bf16 in / fp32 acc) ----------------

__global__ __launch_bounds__(256) void k_agg1(const u16* __restrict__ hs,
                                              const int* __restrict__ offsets,
                                              const int* __restrict__ csr,
                                              const float* __restrict__ dinv,
                                              const float* __restrict__ b,
                                              u16* __restrict__ out) {
    int wave = threadIdx.x >> 6;
    int lane = threadIdx.x & 63;
    int node = blockIdx.x * 4 + wave;
    if (node >= N_NODES) return;
    int beg = offsets[node], end = offsets[node + 1];
    float2 acc = __bfloat1622float2(*(const __hip_bfloat162*)&hs[(size_t)node * HID_F + lane * 2]);
    int j = beg;
    for (; j + 4 <= end; j += 4) {
        int s0 = csr[j], s1 = csr[j + 1], s2 = csr[j + 2], s3 = csr[j + 3];
        float2 v0 = __bfloat1622float2(*(const __hip_bfloat162*)&hs[(size_t)s0 * HID_F + lane * 2]);
        float2 v1 = __bfloat1622float2(*(const __hip_bfloat162*)&hs[(size_t)s1 * HID_F + lane * 2]);
        float2 v2 = __bfloat1622float2(*(const __hip_bfloat162*)&hs[(size_t)s2 * HID_F + lane * 2]);
        float2 v3 = __bfloat1622float2(*(const __hip_bfloat162*)&hs[(size_t)s3 * HID_F + lane * 2]);
        acc.x += v0.x + v1.x + v2.x + v3.x;
        acc.y += v0.y + v1.y + v2.y + v3.y;
    }
    for (; j < end; j++) {
        float2 v = __bfloat1622float2(*(const __hip_bfloat162*)&hs[(size_t)csr[j] * HID_F + lane * 2]);
        acc.x += v.x;
        acc.y += v.y;
    }
    float dv = dinv[node];
    float2 bb = *(const float2*)&b[lane * 2];
    float ox = fmaxf(dv * acc.x + bb.x, 0.f);
    float oy = fmaxf(dv * acc.y + bb.y, 0.f);
    __hip_bfloat162 ob = __float22bfloat162_rn(make_float2(ox, oy));
    *(__hip_bfloat162*)&out[(size_t)node * HID_F + lane * 2] = ob;
}

__global__ __launch_bounds__(256) void k_agg2(const u16* __restrict__ hs,
                                              const int* __restrict__ offsets,
                                              const int* __restrict__ csr,
                                              const float* __restrict__ dinv,
                                              const float* __restrict__ b,
                                              float* __restrict__ out) {
    int wave = threadIdx.x >> 6;
    int lane = threadIdx.x & 63;
    int node = blockIdx.x * 4 + wave;
    if (node >= N_NODES) return;
    int beg = offsets[node], end = offsets[node + 1];
    float acc = __bfloat162float(*(const __hip_bfloat16*)&hs[(size_t)node * OUT_FT + lane]);
    int j = beg;
    for (; j + 4 <= end; j += 4) {
        int s0 = csr[j], s1 = csr[j + 1], s2 = csr[j + 2], s3 = csr[j + 3];
        acc += __bfloat162float(*(const __hip_bfloat16*)&hs[(size_t)s0 * OUT_FT + lane]) +
               __bfloat162float(*(const __hip_bfloat16*)&hs[(size_t)s1 * OUT_FT + lane]) +
               __bfloat162float(*(const __hip_bfloat16*)&hs[(size_t)s2 * OUT_FT + lane]) +
               __bfloat162float(*(const __hip_bfloat16*)&hs[(size_t)s3 * OUT_FT + lane]);
    }
    for (; j < end; j++)
        acc += __bfloat162float(*(const __hip_bfloat16*)&hs[(size_t)csr[j] * OUT_FT + lane]);
    out[(size_t)node * OUT_FT + lane] = dinv[node] * acc + b[lane];
}

// ---------------- launch ----------------

extern "C" void kernel_launch(void* const* d_in, const int* in_sizes, int n_in,
                              void* d_out, int out_size, void* d_ws, size_t ws_size,
                              hipStream_t stream) {
    const float* x  = (const float*)d_in[0];
    const int*   ei = (const int*)d_in[1];  // [2][E]
    const float* W1 = (const float*)d_in[2];
    const float* b1 = (const float*)d_in[3];
    const float* W2 = (const float*)d_in[4];
    const float* b2 = (const float*)d_in[5];
    float* out = (float*)d_out;

    char* ws = (char*)d_ws;
    int*   counts  = (int*)(ws + 0);           // N ints
    int*   offsets = (int*)(ws + 400384);      // N+1 ints
    int*   cursor  = (int*)(ws + 800896);      // N ints (consumed by fill)
    float* dinv    = (float*)(ws + 1201152);   // N floats
    int*   csr     = (int*)(ws + 1601536);     // E ints -> 8001536
    u16*   W1t     = (u16*)(ws + 8001536);     // 128x256 bf16 -> 8067072
    u16*   W2t     = (u16*)(ws + 8067072);     // 64x128 bf16  -> 8083456
    u16*   hs1     = (u16*)(ws + 8083456);     // N*128 bf16 -> 33683456
    u16*   a1      = (u16*)(ws + 33683456);    // N*128 bf16 -> 59283456
    u16*   hs2     = hs1;                      // reuse: hs1 dead after agg1
    int*   blksum  = (int*)(ws + 59283456);
    int*   blkoff  = (int*)(ws + 59283456 + 2048);

    const int* srcA = ei;
    const int* dstA = ei + N_EDGES;

    hipMemsetAsync(counts, 0, N_NODES * sizeof(int), stream);

    k_count_cast<<<G_FILL + G_CAST, 256, 0, stream>>>(dstA, counts, W1, W2, W1t, W2t);
    k_dinv_bsum<<<NBLK_SCAN, 256, 0, stream>>>(counts, dinv, blksum);
    k_scanblk<<<1, 512, 0, stream>>>(blksum, blkoff);
    k_offsets<<<NBLK_SCAN, 256, 0, stream>>>(counts, blkoff, offsets, cursor);

    // fused: layer-1 GEMM (gemm blocks first) + CSR fill backfilling spare slots
    k_gemm1_fill<<<G_GEMM + G_FILL, 256, 0, stream>>>(x, W1t, dinv, hs1,
                                                      srcA, dstA, cursor, csr);

    k_agg1<<<(N_NODES + 3) / 4, 256, 0, stream>>>(hs1, offsets, csr, dinv, b1, a1);
    k_gemm2<<<G_GEMM, 256, 0, stream>>>(a1, W2t, dinv, hs2);
    k_agg2<<<(N_NODES + 3) / 4, 256, 0, stream>>>(hs2, offsets, csr, dinv, b2, out);
}

// Round 5
// 405.859 us; speedup vs baseline: 1.2118x; 1.2118x over previous
//
#include <hip/hip_runtime.h>
#include <hip/hip_bf16.h>

#define N_NODES 100000
#define N_EDGES 1600000
#define IN_FEAT 256
#define HID_F   128
#define OUT_FT  64

#define NBUK   128
#define NPB    782      // nodes per bucket: 128*782 = 100096 >= N
#define BUKCAP 16384    // mean 12500, sigma ~111 -> 16384 is ~35 sigma, safe
#define EPB    8192     // edges per bin block
#define G_BIN  ((N_EDGES + EPB - 1) / EPB)  // 196
#define G_GEMM ((N_NODES + 127) / 128)      // 782
#define G_CAST ((IN_FEAT * HID_F + HID_F * OUT_FT + 255) / 256)  // 160

typedef unsigned short u16;
typedef __attribute__((ext_vector_type(8))) unsigned short u16x8;
typedef __attribute__((ext_vector_type(8))) short short8;
typedef __attribute__((ext_vector_type(4))) float f32x4;

static __device__ inline u16 f2bf(float f) {
    __hip_bfloat16 h = __float2bfloat16(f);
    return *reinterpret_cast<u16*>(&h);
}

// ---------------- pass A: bin edges by dst bucket (+ weight cast piggyback) ----------------

__global__ __launch_bounds__(256) void k_bin(const int* __restrict__ srcA,
                                             const int* __restrict__ dstA,
                                             int* __restrict__ gcur, int2* __restrict__ pairs,
                                             const float* __restrict__ W1,
                                             const float* __restrict__ W2,
                                             u16* __restrict__ W1t, u16* __restrict__ W2t) {
    if (blockIdx.x >= G_BIN) {
        int idx = (blockIdx.x - G_BIN) * 256 + threadIdx.x;
        if (idx < IN_FEAT * HID_F) {
            int k = idx / HID_F, n = idx % HID_F;
            W1t[n * IN_FEAT + k] = f2bf(W1[idx]);
        } else {
            int e2 = idx - IN_FEAT * HID_F;
            if (e2 < HID_F * OUT_FT) {
                int k = e2 / OUT_FT, n = e2 % OUT_FT;
                W2t[n * HID_F + k] = f2bf(W2[e2]);
            }
        }
        return;
    }
    __shared__ int lh[NBUK];
    int t = threadIdx.x;
    int e0 = blockIdx.x * EPB;
    if (t < NBUK) lh[t] = 0;
    __syncthreads();
#pragma unroll
    for (int i = 0; i < EPB / 256; i++) {
        int e = e0 + i * 256 + t;
        if (e < N_EDGES) atomicAdd(&lh[dstA[e] / NPB], 1);
    }
    __syncthreads();
    if (t < NBUK) {
        int c = lh[t];
        lh[t] = atomicAdd(&gcur[t], c);  // lh becomes this block's local base in bucket
    }
    __syncthreads();
#pragma unroll
    for (int i = 0; i < EPB / 256; i++) {
        int e = e0 + i * 256 + t;
        if (e < N_EDGES) {
            int d = dstA[e];
            int b = d / NPB;
            int p = atomicAdd(&lh[b], 1);
            if (p < BUKCAP) pairs[(size_t)b * BUKCAP + p] = make_int2(srcA[e], d);
        }
    }
}

// ---------------- bucket-count exclusive scan (128 values) ----------------

__global__ __launch_bounds__(256) void k_bukscan(const int* __restrict__ gcur,
                                                 int* __restrict__ bbase) {
    __shared__ int sm[256];
    int t = threadIdx.x;
    int v = (t < NBUK) ? gcur[t] : 0;
    sm[t] = v;
    __syncthreads();
    for (int o = 1; o < 256; o <<= 1) {
        int u = (t >= o) ? sm[t - o] : 0;
        __syncthreads();
        sm[t] += u;
        __syncthreads();
    }
    if (t < NBUK) bbase[t] = sm[t] - v;
    if (t == NBUK - 1) bbase[NBUK] = sm[t];
}

// ---------------- pass B: per-bucket CSR fill + offsets + dinv ----------------

__global__ __launch_bounds__(256) void k_fillB(const int2* __restrict__ pairs,
                                               const int* __restrict__ gcnt,
                                               const int* __restrict__ bbase,
                                               int* __restrict__ offsets,
                                               float* __restrict__ dinv,
                                               int* __restrict__ csr) {
    __shared__ int hist[NPB];
    __shared__ int sm[256];
    int b = blockIdx.x, t = threadIdx.x;
    int nbase = b * NPB;
    int nn = min(NPB, N_NODES - nbase);
    int cnt = gcnt[b];
    int ebase = bbase[b];
    const int2* pb = pairs + (size_t)b * BUKCAP;

    for (int i = t; i < NPB; i += 256) hist[i] = 0;
    __syncthreads();
    for (int i = t; i < cnt; i += 256) atomicAdd(&hist[pb[i].y - nbase], 1);
    __syncthreads();

    // exclusive scan over hist[0..nn): thread t owns nodes [4t, 4t+4)
    int base4 = t * 4;
    int c0 = 0, c1 = 0, c2 = 0, c3 = 0;
    if (base4 < NPB) {
        c0 = hist[base4];
        c1 = (base4 + 1 < NPB) ? hist[base4 + 1] : 0;
        c2 = (base4 + 2 < NPB) ? hist[base4 + 2] : 0;
        c3 = (base4 + 3 < NPB) ? hist[base4 + 3] : 0;
    }
    int s = c0 + c1 + c2 + c3;
    sm[t] = s;
    __syncthreads();
    for (int o = 1; o < 256; o <<= 1) {
        int u = (t >= o) ? sm[t - o] : 0;
        __syncthreads();
        sm[t] += u;
        __syncthreads();
    }
    int run = ebase + sm[t] - s;  // absolute csr position for first node of chunk
    __syncthreads();
    int cc[4] = {c0, c1, c2, c3};
#pragma unroll
    for (int q = 0; q < 4; q++) {
        int n = base4 + q;
        if (n < nn) {
            int g = nbase + n;
            offsets[g] = run;
            dinv[g] = rsqrtf((float)(cc[q] + 1));  // +1 self loop
            hist[n] = run;                          // becomes placement cursor
            run += cc[q];
        }
    }
    __syncthreads();
    for (int i = t; i < cnt; i += 256) {
        int2 e = pb[i];
        int p = atomicAdd(&hist[e.y - nbase], 1);
        csr[p] = e.x;
    }
    if (b == NBUK - 1 && t == 0) offsets[N_NODES] = N_EDGES;
}

// ---------------- MFMA bf16 GEMM, layer 1 ----------------

__global__ __launch_bounds__(256) void k_gemm1(const float* __restrict__ A,
                                               const u16* __restrict__ Bt,
                                               const float* __restrict__ dinv,
                                               u16* __restrict__ C) {
    __shared__ u16 As[128][40];
    __shared__ u16 Bs[128][40];
    int tid = threadIdx.x;
    int wv = tid >> 6, lane = tid & 63;
    int m16 = lane & 15, quad = lane >> 4;
    int row0 = blockIdx.x * 128;
    int r = tid >> 1, h = tid & 1;
    int grow_s = row0 + r;
    bool rok = grow_s < N_NODES;

    f32x4 acc[2][8];
#pragma unroll
    for (int i = 0; i < 2; i++)
#pragma unroll
        for (int j = 0; j < 8; j++) acc[i][j] = (f32x4)(0.f);

    for (int k0 = 0; k0 < IN_FEAT; k0 += 32) {
        f32x4 v0 = (f32x4)(0.f), v1 = v0, v2 = v0, v3 = v0;
        if (rok) {
            const f32x4* src = (const f32x4*)&A[(size_t)grow_s * IN_FEAT + k0 + h * 16];
            v0 = src[0]; v1 = src[1]; v2 = src[2]; v3 = src[3];
        }
        u16x8 p0, p1;
#pragma unroll
        for (int j = 0; j < 4; j++) {
            p0[j] = f2bf(v0[j]); p0[4 + j] = f2bf(v1[j]);
            p1[j] = f2bf(v2[j]); p1[4 + j] = f2bf(v3[j]);
        }
        *(u16x8*)&As[r][h * 16] = p0;
        *(u16x8*)&As[r][h * 16 + 8] = p1;
        const u16x8* bsrc = (const u16x8*)&Bt[(size_t)r * IN_FEAT + k0 + h * 16];
        *(u16x8*)&Bs[r][h * 16] = bsrc[0];
        *(u16x8*)&Bs[r][h * 16 + 8] = bsrc[1];
        __syncthreads();

        short8 af0 = *(const short8*)&As[32 * wv + m16][quad * 8];
        short8 af1 = *(const short8*)&As[32 * wv + 16 + m16][quad * 8];
#pragma unroll
        for (int ct = 0; ct < 8; ct++) {
            short8 bf = *(const short8*)&Bs[16 * ct + m16][quad * 8];
            acc[0][ct] = __builtin_amdgcn_mfma_f32_16x16x32_bf16(af0, bf, acc[0][ct], 0, 0, 0);
            acc[1][ct] = __builtin_amdgcn_mfma_f32_16x16x32_bf16(af1, bf, acc[1][ct], 0, 0, 0);
        }
        __syncthreads();
    }
#pragma unroll
    for (int rt = 0; rt < 2; rt++)
#pragma unroll
        for (int r4 = 0; r4 < 4; r4++) {
            int grow = row0 + 32 * wv + 16 * rt + quad * 4 + r4;
            if (grow < N_NODES) {
                float dv = dinv[grow];
#pragma unroll
                for (int ct = 0; ct < 8; ct++)
                    C[(size_t)grow * HID_F + 16 * ct + m16] = f2bf(acc[rt][ct][r4] * dv);
            }
        }
}

// ---------------- MFMA bf16 GEMM, layer 2 ----------------

__global__ __launch_bounds__(256) void k_gemm2(const u16* __restrict__ A,
                                               const u16* __restrict__ Bt,
                                               const float* __restrict__ dinv,
                                               u16* __restrict__ C) {
    __shared__ u16 As[128][40];
    __shared__ u16 Bs[64][40];
    int tid = threadIdx.x;
    int wv = tid >> 6, lane = tid & 63;
    int m16 = lane & 15, quad = lane >> 4;
    int row0 = blockIdx.x * 128;
    int r = tid >> 1, h = tid & 1;
    int grow_s = row0 + r;
    bool rok = grow_s < N_NODES;
    int nb = tid >> 2, q = tid & 3;

    f32x4 acc[2][4];
#pragma unroll
    for (int i = 0; i < 2; i++)
#pragma unroll
        for (int j = 0; j < 4; j++) acc[i][j] = (f32x4)(0.f);

    for (int k0 = 0; k0 < HID_F; k0 += 32) {
        u16x8 a0 = (u16x8)(0), a1v = (u16x8)(0);
        if (rok) {
            const u16x8* src = (const u16x8*)&A[(size_t)grow_s * HID_F + k0 + h * 16];
            a0 = src[0]; a1v = src[1];
        }
        *(u16x8*)&As[r][h * 16] = a0;
        *(u16x8*)&As[r][h * 16 + 8] = a1v;
        *(u16x8*)&Bs[nb][q * 8] = *(const u16x8*)&Bt[(size_t)nb * HID_F + k0 + q * 8];
        __syncthreads();

        short8 af0 = *(const short8*)&As[32 * wv + m16][quad * 8];
        short8 af1 = *(const short8*)&As[32 * wv + 16 + m16][quad * 8];
#pragma unroll
        for (int ct = 0; ct < 4; ct++) {
            short8 bf = *(const short8*)&Bs[16 * ct + m16][quad * 8];
            acc[0][ct] = __builtin_amdgcn_mfma_f32_16x16x32_bf16(af0, bf, acc[0][ct], 0, 0, 0);
            acc[1][ct] = __builtin_amdgcn_mfma_f32_16x16x32_bf16(af1, bf, acc[1][ct], 0, 0, 0);
        }
        __syncthreads();
    }
#pragma unroll
    for (int rt = 0; rt < 2; rt++)
#pragma unroll
        for (int r4 = 0; r4 < 4; r4++) {
            int grow = row0 + 32 * wv + 16 * rt + quad * 4 + r4;
            if (grow < N_NODES) {
                float dv = dinv[grow];
#pragma unroll
                for (int ct = 0; ct < 4; ct++)
                    C[(size_t)grow * OUT_FT + 16 * ct + m16] = f2bf(acc[rt][ct][r4] * dv);
            }
        }
}

// ---------------- aggregation (CSR gather-reduce, bf16 in / fp32 acc) ----------------

__global__ __launch_bounds__(256) void k_agg1(const u16* __restrict__ hs,
                                              const int* __restrict__ offsets,
                                              const int* __restrict__ csr,
                                              const float* __restrict__ dinv,
                                              const float* __restrict__ b,
                                              u16* __restrict__ out) {
    int wave = threadIdx.x >> 6;
    int lane = threadIdx.x & 63;
    int node = blockIdx.x * 4 + wave;
    if (node >= N_NODES) return;
    int beg = offsets[node], end = offsets[node + 1];
    float2 acc = __bfloat1622float2(*(const __hip_bfloat162*)&hs[(size_t)node * HID_F + lane * 2]);
    int j = beg;
    for (; j + 8 <= end; j += 8) {
        int s0 = csr[j], s1 = csr[j + 1], s2 = csr[j + 2], s3 = csr[j + 3];
        int s4 = csr[j + 4], s5 = csr[j + 5], s6 = csr[j + 6], s7 = csr[j + 7];
        float2 v0 = __bfloat1622float2(*(const __hip_bfloat162*)&hs[(size_t)s0 * HID_F + lane * 2]);
        float2 v1 = __bfloat1622float2(*(const __hip_bfloat162*)&hs[(size_t)s1 * HID_F + lane * 2]);
        float2 v2 = __bfloat1622float2(*(const __hip_bfloat162*)&hs[(size_t)s2 * HID_F + lane * 2]);
        float2 v3 = __bfloat1622float2(*(const __hip_bfloat162*)&hs[(size_t)s3 * HID_F + lane * 2]);
        float2 v4 = __bfloat1622float2(*(const __hip_bfloat162*)&hs[(size_t)s4 * HID_F + lane * 2]);
        float2 v5 = __bfloat1622float2(*(const __hip_bfloat162*)&hs[(size_t)s5 * HID_F + lane * 2]);
        float2 v6 = __bfloat1622float2(*(const __hip_bfloat162*)&hs[(size_t)s6 * HID_F + lane * 2]);
        float2 v7 = __bfloat1622float2(*(const __hip_bfloat162*)&hs[(size_t)s7 * HID_F + lane * 2]);
        acc.x += ((v0.x + v1.x) + (v2.x + v3.x)) + ((v4.x + v5.x) + (v6.x + v7.x));
        acc.y += ((v0.y + v1.y) + (v2.y + v3.y)) + ((v4.y + v5.y) + (v6.y + v7.y));
    }
    for (; j < end; j++) {
        float2 v = __bfloat1622float2(*(const __hip_bfloat162*)&hs[(size_t)csr[j] * HID_F + lane * 2]);
        acc.x += v.x;
        acc.y += v.y;
    }
    float dv = dinv[node];
    float2 bb = *(const float2*)&b[lane * 2];
    float ox = fmaxf(dv * acc.x + bb.x, 0.f);
    float oy = fmaxf(dv * acc.y + bb.y, 0.f);
    __hip_bfloat162 ob = __float22bfloat162_rn(make_float2(ox, oy));
    *(__hip_bfloat162*)&out[(size_t)node * HID_F + lane * 2] = ob;
}

__global__ __launch_bounds__(256) void k_agg2(const u16* __restrict__ hs,
                                              const int* __restrict__ offsets,
                                              const int* __restrict__ csr,
                                              const float* __restrict__ dinv,
                                              const float* __restrict__ b,
                                              float* __restrict__ out) {
    int wave = threadIdx.x >> 6;
    int lane = threadIdx.x & 63;
    int node = blockIdx.x * 4 + wave;
    if (node >= N_NODES) return;
    int beg = offsets[node], end = offsets[node + 1];
    float acc = __bfloat162float(*(const __hip_bfloat16*)&hs[(size_t)node * OUT_FT + lane]);
    int j = beg;
    for (; j + 8 <= end; j += 8) {
        int s0 = csr[j], s1 = csr[j + 1], s2 = csr[j + 2], s3 = csr[j + 3];
        int s4 = csr[j + 4], s5 = csr[j + 5], s6 = csr[j + 6], s7 = csr[j + 7];
        float v0 = __bfloat162float(*(const __hip_bfloat16*)&hs[(size_t)s0 * OUT_FT + lane]);
        float v1 = __bfloat162float(*(const __hip_bfloat16*)&hs[(size_t)s1 * OUT_FT + lane]);
        float v2 = __bfloat162float(*(const __hip_bfloat16*)&hs[(size_t)s2 * OUT_FT + lane]);
        float v3 = __bfloat162float(*(const __hip_bfloat16*)&hs[(size_t)s3 * OUT_FT + lane]);
        float v4 = __bfloat162float(*(const __hip_bfloat16*)&hs[(size_t)s4 * OUT_FT + lane]);
        float v5 = __bfloat162float(*(const __hip_bfloat16*)&hs[(size_t)s5 * OUT_FT + lane]);
        float v6 = __bfloat162float(*(const __hip_bfloat16*)&hs[(size_t)s6 * OUT_FT + lane]);
        float v7 = __bfloat162float(*(const __hip_bfloat16*)&hs[(size_t)s7 * OUT_FT + lane]);
        acc += ((v0 + v1) + (v2 + v3)) + ((v4 + v5) + (v6 + v7));
    }
    for (; j < end; j++)
        acc += __bfloat162float(*(const __hip_bfloat16*)&hs[(size_t)csr[j] * OUT_FT + lane]);
    out[(size_t)node * OUT_FT + lane] = dinv[node] * acc + b[lane];
}

// ---------------- launch ----------------

extern "C" void kernel_launch(void* const* d_in, const int* in_sizes, int n_in,
                              void* d_out, int out_size, void* d_ws, size_t ws_size,
                              hipStream_t stream) {
    const float* x  = (const float*)d_in[0];
    const int*   ei = (const int*)d_in[1];  // [2][E]
    const float* W1 = (const float*)d_in[2];
    const float* b1 = (const float*)d_in[3];
    const float* W2 = (const float*)d_in[4];
    const float* b2 = (const float*)d_in[5];
    float* out = (float*)d_out;

    char* ws = (char*)d_ws;
    int*   offsets = (int*)(ws + 0);          // (N+1) ints -> 400512
    float* dinv    = (float*)(ws + 400512);   // N floats   -> 800512
    int*   csr     = (int*)(ws + 800512);     // E ints     -> 7200512
    u16*   W1t     = (u16*)(ws + 7200512);    // 128x256    -> 7266048
    u16*   W2t     = (u16*)(ws + 7266048);    // 64x128     -> 7282432
    int*   gcur    = (int*)(ws + 7282432);    // 128 ints   -> 7282944
    int*   bbase   = (int*)(ws + 7282944);    // 129 ints   -> 7283968 (padded)
    u16*   hs1     = (u16*)(ws + 7283968);    // N*128 bf16 -> 32883968
    u16*   a1      = (u16*)(ws + 32883968);   // N*128 bf16 -> 58483968
    int2*  pairs   = (int2*)(ws + 32883968);  // 16.78 MB, dead before agg1 writes a1
    u16*   hs2     = hs1;                     // hs1 dead after agg1

    const int* srcA = ei;
    const int* dstA = ei + N_EDGES;

    hipMemsetAsync(gcur, 0, NBUK * sizeof(int), stream);

    k_bin<<<G_BIN + G_CAST, 256, 0, stream>>>(srcA, dstA, gcur, pairs, W1, W2, W1t, W2t);
    k_bukscan<<<1, 256, 0, stream>>>(gcur, bbase);
    k_fillB<<<NBUK, 256, 0, stream>>>(pairs, gcur, bbase, offsets, dinv, csr);

    k_gemm1<<<G_GEMM, 256, 0, stream>>>(x, W1t, dinv, hs1);
    k_agg1<<<(N_NODES + 3) / 4, 256, 0, stream>>>(hs1, offsets, csr, dinv, b1, a1);
    k_gemm2<<<G_GEMM, 256, 0, stream>>>(a1, W2t, dinv, hs2);
    k_agg2<<<(N_NODES + 3) / 4, 256, 0, stream>>>(hs2, offsets, csr, dinv, b2, out);
}

// Round 6
// 356.365 us; speedup vs baseline: 1.3801x; 1.1389x over previous
//
#include <hip/hip_runtime.h>
#include <hip/hip_bf16.h>

#define N_NODES 100000
#define N_EDGES 1600000
#define IN_FEAT 256
#define HID_F   128
#define OUT_FT  64

#define NBUK   256
#define NPB    391      // nodes per bucket: 256*391 = 100096 >= N
#define BUKCAP 8192     // mean 6250, sigma ~79 -> +24 sigma, safe
#define EPB    4096     // edges per bin block
#define G_BIN  ((N_EDGES + EPB - 1) / EPB)  // 391
#define G_GEMM ((N_NODES + 127) / 128)      // 782
#define G_CAST ((IN_FEAT * HID_F + HID_F * OUT_FT + 255) / 256)  // 160

typedef unsigned short u16;
typedef __attribute__((ext_vector_type(8))) unsigned short u16x8;
typedef __attribute__((ext_vector_type(8))) short short8;
typedef __attribute__((ext_vector_type(4))) float f32x4;

static __device__ inline u16 f2bf(float f) {
    __hip_bfloat16 h = __float2bfloat16(f);
    return *reinterpret_cast<u16*>(&h);
}
static __device__ inline float bf2f(u16 u) {
    union { unsigned u; float f; } c;
    c.u = ((unsigned)u) << 16;
    return c.f;
}

// ---------------- pass A: bin edges by dst bucket (+ weight cast piggyback) ----------------

__global__ __launch_bounds__(256) void k_bin(const int* __restrict__ srcA,
                                             const int* __restrict__ dstA,
                                             int* __restrict__ gcur, int2* __restrict__ pairs,
                                             const float* __restrict__ W1,
                                             const float* __restrict__ W2,
                                             u16* __restrict__ W1t, u16* __restrict__ W2t) {
    if (blockIdx.x >= G_BIN) {
        int idx = (blockIdx.x - G_BIN) * 256 + threadIdx.x;
        if (idx < IN_FEAT * HID_F) {
            int k = idx / HID_F, n = idx % HID_F;
            W1t[n * IN_FEAT + k] = f2bf(W1[idx]);
        } else {
            int e2 = idx - IN_FEAT * HID_F;
            if (e2 < HID_F * OUT_FT) {
                int k = e2 / OUT_FT, n = e2 % OUT_FT;
                W2t[n * HID_F + k] = f2bf(W2[e2]);
            }
        }
        return;
    }
    __shared__ int lh[NBUK];
    int t = threadIdx.x;
    int e0 = blockIdx.x * EPB;
    if (t < NBUK) lh[t] = 0;
    __syncthreads();
#pragma unroll
    for (int i = 0; i < EPB / 256; i++) {
        int e = e0 + i * 256 + t;
        if (e < N_EDGES) atomicAdd(&lh[dstA[e] / NPB], 1);
    }
    __syncthreads();
    if (t < NBUK) {
        int c = lh[t];
        lh[t] = atomicAdd(&gcur[t], c);  // becomes this block's base in bucket
    }
    __syncthreads();
#pragma unroll
    for (int i = 0; i < EPB / 256; i++) {
        int e = e0 + i * 256 + t;
        if (e < N_EDGES) {
            int d = dstA[e];
            int b = d / NPB;
            int p = atomicAdd(&lh[b], 1);
            if (p < BUKCAP) pairs[(size_t)b * BUKCAP + p] = make_int2(srcA[e], d);
        }
    }
}

// ---------------- bucket-count exclusive scan (256 values) ----------------

__global__ __launch_bounds__(256) void k_bukscan(const int* __restrict__ gcur,
                                                 int* __restrict__ bbase) {
    __shared__ int sm[256];
    int t = threadIdx.x;
    int v = gcur[t];
    sm[t] = v;
    __syncthreads();
    for (int o = 1; o < 256; o <<= 1) {
        int u = (t >= o) ? sm[t - o] : 0;
        __syncthreads();
        sm[t] += u;
        __syncthreads();
    }
    bbase[t] = sm[t] - v;
    if (t == NBUK - 1) bbase[NBUK] = sm[t];
}

// ---------------- pass B: per-bucket CSR fill + offsets + dinv ----------------

__global__ __launch_bounds__(256) void k_fillB(const int2* __restrict__ pairs,
                                               const int* __restrict__ gcnt,
                                               const int* __restrict__ bbase,
                                               int* __restrict__ offsets,
                                               float* __restrict__ dinv,
                                               int* __restrict__ csr) {
    __shared__ int hist[NPB];
    __shared__ int sm[256];
    int b = blockIdx.x, t = threadIdx.x;
    int nbase = b * NPB;
    int nn = min(NPB, N_NODES - nbase);
    int cnt = gcnt[b];
    int ebase = bbase[b];
    const int2* pb = pairs + (size_t)b * BUKCAP;

    for (int i = t; i < NPB; i += 256) hist[i] = 0;
    __syncthreads();
    for (int i = t; i < cnt; i += 256) atomicAdd(&hist[pb[i].y - nbase], 1);
    __syncthreads();

    // exclusive scan over hist[0..nn): thread t owns nodes [2t, 2t+2)
    int base2 = t * 2;
    int c0 = (base2 < NPB) ? hist[base2] : 0;
    int c1 = (base2 + 1 < NPB) ? hist[base2 + 1] : 0;
    int s = c0 + c1;
    sm[t] = s;
    __syncthreads();
    for (int o = 1; o < 256; o <<= 1) {
        int u = (t >= o) ? sm[t - o] : 0;
        __syncthreads();
        sm[t] += u;
        __syncthreads();
    }
    int run = ebase + sm[t] - s;
    __syncthreads();
    int cc[2] = {c0, c1};
#pragma unroll
    for (int q = 0; q < 2; q++) {
        int n = base2 + q;
        if (n < nn) {
            int g = nbase + n;
            offsets[g] = run;
            dinv[g] = rsqrtf((float)(cc[q] + 1));  // +1 self loop
            hist[n] = run;                          // becomes placement cursor
            run += cc[q];
        }
    }
    __syncthreads();
    for (int i = t; i < cnt; i += 256) {
        int2 e = pb[i];
        int p = atomicAdd(&hist[e.y - nbase], 1);
        csr[p] = e.x;
    }
    if (b == NBUK - 1 && t == 0) offsets[N_NODES] = N_EDGES;
}

// ---------------- MFMA bf16 GEMM, layer 1 ----------------

__global__ __launch_bounds__(256) void k_gemm1(const float* __restrict__ A,
                                               const u16* __restrict__ Bt,
                                               const float* __restrict__ dinv,
                                               u16* __restrict__ C) {
    __shared__ u16 As[128][40];
    __shared__ u16 Bs[128][40];
    int tid = threadIdx.x;
    int wv = tid >> 6, lane = tid & 63;
    int m16 = lane & 15, quad = lane >> 4;
    int row0 = blockIdx.x * 128;
    int r = tid >> 1, h = tid & 1;
    int grow_s = row0 + r;
    bool rok = grow_s < N_NODES;

    f32x4 acc[2][8];
#pragma unroll
    for (int i = 0; i < 2; i++)
#pragma unroll
        for (int j = 0; j < 8; j++) acc[i][j] = (f32x4)(0.f);

    for (int k0 = 0; k0 < IN_FEAT; k0 += 32) {
        f32x4 v0 = (f32x4)(0.f), v1 = v0, v2 = v0, v3 = v0;
        if (rok) {
            const f32x4* src = (const f32x4*)&A[(size_t)grow_s * IN_FEAT + k0 + h * 16];
            v0 = src[0]; v1 = src[1]; v2 = src[2]; v3 = src[3];
        }
        u16x8 p0, p1;
#pragma unroll
        for (int j = 0; j < 4; j++) {
            p0[j] = f2bf(v0[j]); p0[4 + j] = f2bf(v1[j]);
            p1[j] = f2bf(v2[j]); p1[4 + j] = f2bf(v3[j]);
        }
        *(u16x8*)&As[r][h * 16] = p0;
        *(u16x8*)&As[r][h * 16 + 8] = p1;
        const u16x8* bsrc = (const u16x8*)&Bt[(size_t)r * IN_FEAT + k0 + h * 16];
        *(u16x8*)&Bs[r][h * 16] = bsrc[0];
        *(u16x8*)&Bs[r][h * 16 + 8] = bsrc[1];
        __syncthreads();

        short8 af0 = *(const short8*)&As[32 * wv + m16][quad * 8];
        short8 af1 = *(const short8*)&As[32 * wv + 16 + m16][quad * 8];
#pragma unroll
        for (int ct = 0; ct < 8; ct++) {
            short8 bf = *(const short8*)&Bs[16 * ct + m16][quad * 8];
            acc[0][ct] = __builtin_amdgcn_mfma_f32_16x16x32_bf16(af0, bf, acc[0][ct], 0, 0, 0);
            acc[1][ct] = __builtin_amdgcn_mfma_f32_16x16x32_bf16(af1, bf, acc[1][ct], 0, 0, 0);
        }
        __syncthreads();
    }
#pragma unroll
    for (int rt = 0; rt < 2; rt++)
#pragma unroll
        for (int r4 = 0; r4 < 4; r4++) {
            int grow = row0 + 32 * wv + 16 * rt + quad * 4 + r4;
            if (grow < N_NODES) {
                float dv = dinv[grow];
#pragma unroll
                for (int ct = 0; ct < 8; ct++)
                    C[(size_t)grow * HID_F + 16 * ct + m16] = f2bf(acc[rt][ct][r4] * dv);
            }
        }
}

// ---------------- MFMA bf16 GEMM, layer 2 ----------------

__global__ __launch_bounds__(256) void k_gemm2(const u16* __restrict__ A,
                                               const u16* __restrict__ Bt,
                                               const float* __restrict__ dinv,
                                               u16* __restrict__ C) {
    __shared__ u16 As[128][40];
    __shared__ u16 Bs[64][40];
    int tid = threadIdx.x;
    int wv = tid >> 6, lane = tid & 63;
    int m16 = lane & 15, quad = lane >> 4;
    int row0 = blockIdx.x * 128;
    int r = tid >> 1, h = tid & 1;
    int grow_s = row0 + r;
    bool rok = grow_s < N_NODES;
    int nb = tid >> 2, q = tid & 3;

    f32x4 acc[2][4];
#pragma unroll
    for (int i = 0; i < 2; i++)
#pragma unroll
        for (int j = 0; j < 4; j++) acc[i][j] = (f32x4)(0.f);

    for (int k0 = 0; k0 < HID_F; k0 += 32) {
        u16x8 a0 = (u16x8)(0), a1v = (u16x8)(0);
        if (rok) {
            const u16x8* src = (const u16x8*)&A[(size_t)grow_s * HID_F + k0 + h * 16];
            a0 = src[0]; a1v = src[1];
        }
        *(u16x8*)&As[r][h * 16] = a0;
        *(u16x8*)&As[r][h * 16 + 8] = a1v;
        *(u16x8*)&Bs[nb][q * 8] = *(const u16x8*)&Bt[(size_t)nb * HID_F + k0 + q * 8];
        __syncthreads();

        short8 af0 = *(const short8*)&As[32 * wv + m16][quad * 8];
        short8 af1 = *(const short8*)&As[32 * wv + 16 + m16][quad * 8];
#pragma unroll
        for (int ct = 0; ct < 4; ct++) {
            short8 bf = *(const short8*)&Bs[16 * ct + m16][quad * 8];
            acc[0][ct] = __builtin_amdgcn_mfma_f32_16x16x32_bf16(af0, bf, acc[0][ct], 0, 0, 0);
            acc[1][ct] = __builtin_amdgcn_mfma_f32_16x16x32_bf16(af1, bf, acc[1][ct], 0, 0, 0);
        }
        __syncthreads();
    }
#pragma unroll
    for (int rt = 0; rt < 2; rt++)
#pragma unroll
        for (int r4 = 0; r4 < 4; r4++) {
            int grow = row0 + 32 * wv + 16 * rt + quad * 4 + r4;
            if (grow < N_NODES) {
                float dv = dinv[grow];
#pragma unroll
                for (int ct = 0; ct < 4; ct++)
                    C[(size_t)grow * OUT_FT + 16 * ct + m16] = f2bf(acc[rt][ct][r4] * dv);
            }
        }
}

// ---------------- aggregation: wide-gather CSR reduce ----------------
// agg1: one wave per node; 16 lanes x 16B cover a 256B row; 4 edges per load instr.

__global__ __launch_bounds__(256) void k_agg1(const u16* __restrict__ hs,
                                              const int* __restrict__ offsets,
                                              const int* __restrict__ csr,
                                              const float* __restrict__ dinv,
                                              const float* __restrict__ b,
                                              u16* __restrict__ out) {
    int wave = threadIdx.x >> 6;
    int lane = threadIdx.x & 63;
    int node = blockIdx.x * 4 + wave;
    if (node >= N_NODES) return;
    int g = lane >> 4;        // edge sub-group 0..3
    int fl = lane & 15;       // feature-block lane
    const int fo = fl * 8;    // 8 features per lane
    int beg = offsets[node], end = offsets[node + 1];

    float acc[8];
#pragma unroll
    for (int i = 0; i < 8; i++) acc[i] = 0.f;

    int j = beg;
    for (; j + 8 <= end; j += 8) {  // 8 edges per iter (2 per group)
        int s0 = csr[j + g];
        int s1 = csr[j + 4 + g];
        u16x8 r0 = *(const u16x8*)&hs[(size_t)s0 * HID_F + fo];
        u16x8 r1 = *(const u16x8*)&hs[(size_t)s1 * HID_F + fo];
#pragma unroll
        for (int i = 0; i < 8; i++) acc[i] += bf2f(r0[i]) + bf2f(r1[i]);
    }
    for (; j < end; j += 4) {
        int idx = j + g;
        if (idx < end) {
            int s = csr[idx];
            u16x8 r0 = *(const u16x8*)&hs[(size_t)s * HID_F + fo];
#pragma unroll
            for (int i = 0; i < 8; i++) acc[i] += bf2f(r0[i]);
        }
    }
    // butterfly-reduce across the 4 edge groups
#pragma unroll
    for (int i = 0; i < 8; i++) {
        acc[i] += __shfl_xor(acc[i], 16, 64);
        acc[i] += __shfl_xor(acc[i], 32, 64);
    }
    // self loop (each lane adds its own slice once, post-reduction)
    u16x8 sr = *(const u16x8*)&hs[(size_t)node * HID_F + fo];
#pragma unroll
    for (int i = 0; i < 8; i++) acc[i] += bf2f(sr[i]);

    if (g == 0) {
        float dv = dinv[node];
        f32x4 b0 = *(const f32x4*)&b[fo];
        f32x4 b1 = *(const f32x4*)&b[fo + 4];
        u16x8 o;
#pragma unroll
        for (int i = 0; i < 4; i++) {
            o[i] = f2bf(fmaxf(dv * acc[i] + b0[i], 0.f));
            o[4 + i] = f2bf(fmaxf(dv * acc[4 + i] + b1[i], 0.f));
        }
        *(u16x8*)&out[(size_t)node * HID_F + fo] = o;
    }
}

// agg2: 8 lanes x 16B cover a 128B row; 8 edges per load instr; fp32 out.

__global__ __launch_bounds__(256) void k_agg2(const u16* __restrict__ hs,
                                              const int* __restrict__ offsets,
                                              const int* __restrict__ csr,
                                              const float* __restrict__ dinv,
                                              const float* __restrict__ b,
                                              float* __restrict__ out) {
    int wave = threadIdx.x >> 6;
    int lane = threadIdx.x & 63;
    int node = blockIdx.x * 4 + wave;
    if (node >= N_NODES) return;
    int g = lane >> 3;        // edge sub-group 0..7
    int fl = lane & 7;        // feature-block lane
    const int fo = fl * 8;
    int beg = offsets[node], end = offsets[node + 1];

    float acc[8];
#pragma unroll
    for (int i = 0; i < 8; i++) acc[i] = 0.f;

    int j = beg;
    for (; j + 16 <= end; j += 16) {  // 16 edges per iter (2 per group)
        int s0 = csr[j + g];
        int s1 = csr[j + 8 + g];
        u16x8 r0 = *(const u16x8*)&hs[(size_t)s0 * OUT_FT + fo];
        u16x8 r1 = *(const u16x8*)&hs[(size_t)s1 * OUT_FT + fo];
#pragma unroll
        for (int i = 0; i < 8; i++) acc[i] += bf2f(r0[i]) + bf2f(r1[i]);
    }
    for (; j < end; j += 8) {
        int idx = j + g;
        if (idx < end) {
            int s = csr[idx];
            u16x8 r0 = *(const u16x8*)&hs[(size_t)s * OUT_FT + fo];
#pragma unroll
            for (int i = 0; i < 8; i++) acc[i] += bf2f(r0[i]);
        }
    }
#pragma unroll
    for (int i = 0; i < 8; i++) {
        acc[i] += __shfl_xor(acc[i], 8, 64);
        acc[i] += __shfl_xor(acc[i], 16, 64);
        acc[i] += __shfl_xor(acc[i], 32, 64);
    }
    u16x8 sr = *(const u16x8*)&hs[(size_t)node * OUT_FT + fo];
#pragma unroll
    for (int i = 0; i < 8; i++) acc[i] += bf2f(sr[i]);

    if (g == 0) {
        float dv = dinv[node];
        f32x4 b0 = *(const f32x4*)&b[fo];
        f32x4 b1 = *(const f32x4*)&b[fo + 4];
        f32x4 o0, o1;
#pragma unroll
        for (int i = 0; i < 4; i++) {
            o0[i] = dv * acc[i] + b0[i];
            o1[i] = dv * acc[4 + i] + b1[i];
        }
        *(f32x4*)&out[(size_t)node * OUT_FT + fo] = o0;
        *(f32x4*)&out[(size_t)node * OUT_FT + fo + 4] = o1;
    }
}

// ---------------- launch ----------------

extern "C" void kernel_launch(void* const* d_in, const int* in_sizes, int n_in,
                              void* d_out, int out_size, void* d_ws, size_t ws_size,
                              hipStream_t stream) {
    const float* x  = (const float*)d_in[0];
    const int*   ei = (const int*)d_in[1];  // [2][E]
    const float* W1 = (const float*)d_in[2];
    const float* b1 = (const float*)d_in[3];
    const float* W2 = (const float*)d_in[4];
    const float* b2 = (const float*)d_in[5];
    float* out = (float*)d_out;

    char* ws = (char*)d_ws;
    int*   offsets = (int*)(ws + 0);          // (N+1) ints -> 400512
    float* dinv    = (float*)(ws + 400512);   // N floats   -> 800512
    int*   csr     = (int*)(ws + 800512);     // E ints     -> 7200512
    u16*   W1t     = (u16*)(ws + 7200512);    // 128x256    -> 7266048
    u16*   W2t     = (u16*)(ws + 7266048);    // 64x128     -> 7282432
    int*   gcur    = (int*)(ws + 7282432);    // 256 ints   -> 7283456
    int*   bbase   = (int*)(ws + 7283456);    // 257 ints   -> 7284608 (padded)
    u16*   hs1     = (u16*)(ws + 7284608);    // N*128 bf16 -> 32884608
    u16*   a1      = (u16*)(ws + 32884608);   // N*128 bf16 -> 58484608
    int2*  pairs   = (int2*)(ws + 32884608);  // 16.78 MB, dead before agg1 writes a1
    u16*   hs2     = hs1;                     // hs1 dead after agg1

    const int* srcA = ei;
    const int* dstA = ei + N_EDGES;

    hipMemsetAsync(gcur, 0, NBUK * sizeof(int), stream);

    k_bin<<<G_BIN + G_CAST, 256, 0, stream>>>(srcA, dstA, gcur, pairs, W1, W2, W1t, W2t);
    k_bukscan<<<1, 256, 0, stream>>>(gcur, bbase);
    k_fillB<<<NBUK, 256, 0, stream>>>(pairs, gcur, bbase, offsets, dinv, csr);

    k_gemm1<<<G_GEMM, 256, 0, stream>>>(x, W1t, dinv, hs1);
    k_agg1<<<(N_NODES + 3) / 4, 256, 0, stream>>>(hs1, offsets, csr, dinv, b1, a1);
    k_gemm2<<<G_GEMM, 256, 0, stream>>>(a1, W2t, dinv, hs2);
    k_agg2<<<(N_NODES + 3) / 4, 256, 0, stream>>>(hs2, offsets, csr, dinv, b2, out);
}